// Round 4
// baseline (311.198 us; speedup 1.0000x reference)
//
#include <hip/hip_runtime.h>

#define N_NODES 100000
#define NUM_TYPES 8
#define FACTOR 0.125f      // 1/sqrt(64)

#define S_CHUNK 16384      // power of 2: bucket = center >> 14, lidx = center & 16383
#define C_MAX 7            // supports N <= 114688
#define NBLK_AB 1024       // blocks for count/scatter (contiguous edge ranges)
#define THR_AB 512
#define THR_C 1024
#define B_MAX 73           // segments per bucket in accumulate -> grid 7*73 = 511 (~2/CU)

// ---------- Kernel A: per-block bucket histogram + u8 type table ----------
__global__ __launch_bounds__(THR_AB) void count_kernel(
    const int* __restrict__ centers,
    const int* __restrict__ atom_type,
    unsigned char* __restrict__ tt,        // [N] u8 type table
    unsigned int* __restrict__ blockhist,  // [NBLK_AB][C_MAX]
    unsigned int* __restrict__ totals,     // [C_MAX] (pre-zeroed)
    int E, int N)
{
    __shared__ unsigned int s_h[C_MAX];
    if (threadIdx.x < C_MAX) s_h[threadIdx.x] = 0;
    __syncthreads();

    // build dense u8 type table (whole-grid stride)
    for (int j = blockIdx.x * blockDim.x + threadIdx.x; j < N; j += gridDim.x * blockDim.x)
        tt[j] = (unsigned char)atom_type[j];

    const int n4  = E >> 2;
    const int qpb = (n4 + NBLK_AB - 1) / NBLK_AB;
    const int q0  = blockIdx.x * qpb;
    const int q1  = min(n4, q0 + qpb);

    unsigned h0=0,h1=0,h2=0,h3=0,h4=0,h5=0,h6=0;
    for (int i = q0 + (int)threadIdx.x; i < q1; i += THR_AB) {
        int4 cc = ((const int4*)centers)[i];
#define CNT(v) { unsigned b = ((unsigned)(v)) >> 14; \
        h0 += (b==0); h1 += (b==1); h2 += (b==2); h3 += (b==3); \
        h4 += (b==4); h5 += (b==5); h6 += (b==6); }
        CNT(cc.x) CNT(cc.y) CNT(cc.z) CNT(cc.w)
#undef CNT
    }
    if (blockIdx.x == 0) {      // tail edges (E % 4)
        for (int i = (n4 << 2) + (int)threadIdx.x; i < E; i += THR_AB) {
            unsigned b = ((unsigned)centers[i]) >> 14;
            h0 += (b==0); h1 += (b==1); h2 += (b==2); h3 += (b==3);
            h4 += (b==4); h5 += (b==5); h6 += (b==6);
        }
    }
    atomicAdd(&s_h[0], h0); atomicAdd(&s_h[1], h1); atomicAdd(&s_h[2], h2);
    atomicAdd(&s_h[3], h3); atomicAdd(&s_h[4], h4); atomicAdd(&s_h[5], h5);
    atomicAdd(&s_h[6], h6);
    __syncthreads();
    if (threadIdx.x < C_MAX) {
        unsigned v = s_h[threadIdx.x];
        blockhist[blockIdx.x * C_MAX + threadIdx.x] = v;
        atomicAdd(&totals[threadIdx.x], v);
    }
}

// ---------- Kernel B: compute val, scatter (lidx, val) pairs into buckets ----------
// Wave-ballot slot aggregation: 7 ballots partition the wave by bucket; one
// leader lane per bucket does a single ds_add_rtn (7 lanes, 7 distinct LDS
// addresses -> parallel banks); others get slots via shfl + prefix popcount.
// LDS atomics drop 64x vs per-edge cursors, and each wave's bucket-k pairs
// land in a contiguous slot run (coalesced stores).
__global__ __launch_bounds__(THR_AB) void scatter_kernel(
    const int* __restrict__ centers,
    const int* __restrict__ neighbors,
    const float* __restrict__ eng,
    const unsigned char* __restrict__ tt,
    const float* __restrict__ scales,
    const unsigned int* __restrict__ blockhist,
    const unsigned int* __restrict__ totals,
    unsigned int* __restrict__ cursors,    // [C_MAX] (pre-zeroed)
    uint2* __restrict__ pairs,             // [E] compacted per bucket
    int E)
{
    __shared__ unsigned int s_cur[C_MAX];   // intra-block relative cursor
    __shared__ unsigned int s_base[C_MAX];  // absolute slot base for this block
    __shared__ unsigned int s_res[C_MAX], s_tot[C_MAX];
    __shared__ float s_scales[NUM_TYPES * NUM_TYPES];

    if (threadIdx.x < NUM_TYPES * NUM_TYPES)
        s_scales[threadIdx.x] = scales[threadIdx.x] * FACTOR;   // fold FACTOR
    if (threadIdx.x < C_MAX) {
        unsigned h = blockhist[blockIdx.x * C_MAX + threadIdx.x];
        s_res[threadIdx.x] = atomicAdd(&cursors[threadIdx.x], h);  // reserve [res, res+h)
        s_tot[threadIdx.x] = totals[threadIdx.x];
        s_cur[threadIdx.x] = 0;
    }
    __syncthreads();
    if (threadIdx.x == 0) {               // bucket base = exclusive scan of totals
        unsigned run = 0;
        for (int b = 0; b < C_MAX; ++b) { s_base[b] = run + s_res[b]; run += s_tot[b]; }
    }
    __syncthreads();

    const int lane = (int)(threadIdx.x & 63);
    const unsigned long long lanemask_lt = (lane == 63) ? 0x7fffffffffffffffull
                                                        : ((1ull << lane) - 1ull);

    const int n4  = E >> 2;
    const int qpb = (n4 + NBLK_AB - 1) / NBLK_AB;
    const int q0  = blockIdx.x * qpb;
    const int q1  = min(n4, q0 + qpb);

    for (int i = q0 + (int)threadIdx.x; i < q1; i += THR_AB) {
        int4   cc = ((const int4*)centers)[i];
        int4   nn = ((const int4*)neighbors)[i];
        float4 e  = ((const float4*)eng)[i];

#define POS(C_, N_, E_) { \
        unsigned b = ((unsigned)(C_)) >> 14; \
        float v = (E_) * s_scales[(int)tt[C_] * NUM_TYPES + (int)tt[N_]]; \
        unsigned long long mymask = 0; \
        _Pragma("unroll") \
        for (int k = 0; k < C_MAX; ++k) { \
            unsigned long long mk = __ballot(b == (unsigned)k); \
            if (b == (unsigned)k) mymask = mk; \
        } \
        int leader = __ffsll((unsigned long long)mymask) - 1; \
        unsigned old = 0; \
        if (lane == leader) old = atomicAdd(&s_cur[b], (unsigned)__popcll(mymask)); \
        old = (unsigned)__shfl((int)old, leader); \
        unsigned slot = s_base[b] + old + (unsigned)__popcll(mymask & lanemask_lt); \
        pairs[slot] = make_uint2(((unsigned)(C_)) & (S_CHUNK - 1), __float_as_uint(v)); }

        POS(cc.x, nn.x, e.x) POS(cc.y, nn.y, e.y)
        POS(cc.z, nn.z, e.z) POS(cc.w, nn.w, e.w)
#undef POS
    }
    if (blockIdx.x == 0) {      // tail edges (E % 4) — counted in block 0's hist
        for (int i = (n4 << 2) + (int)threadIdx.x; i < E; i += THR_AB) {
            int c = centers[i];
            unsigned b = ((unsigned)c) >> 14;
            float v = eng[i] * s_scales[(int)tt[c] * NUM_TYPES + (int)tt[neighbors[i]]];
            unsigned slot = s_base[b] + atomicAdd(&s_cur[b], 1u);
            pairs[slot] = make_uint2(((unsigned)c) & (S_CHUNK - 1), __float_as_uint(v));
        }
    }
}

// ---------- Kernel C: per-bucket LDS-bin accumulate (single scan of pairs) ----------
__global__ __launch_bounds__(THR_C) void bucket_sum_kernel(
    const uint2* __restrict__ pairs,
    const unsigned int* __restrict__ totals,
    float* __restrict__ partials,          // [C_MAX][B][S_CHUNK]
    int B)
{
    __shared__ float bins[S_CHUNK];
    const int c = blockIdx.x / B;
    const int s = blockIdx.x % B;

    for (int j = threadIdx.x; j < S_CHUNK; j += THR_C) bins[j] = 0.0f;

    unsigned base = 0, cnt = 0;            // wave-uniform scan of 7 totals
    for (int b = 0; b < C_MAX; ++b) {
        unsigned t = totals[b];
        if (b <  c) base += t;
        if (b == c) cnt = t;
    }
    __syncthreads();

    for (unsigned i = (unsigned)s * THR_C + threadIdx.x; i < cnt; i += (unsigned)B * THR_C) {
        uint2 p = pairs[base + i];
        atomicAdd(&bins[p.x], __uint_as_float(p.y));
    }

    __syncthreads();
    float* dst = partials + ((size_t)c * B + s) * S_CHUNK;
    for (int j = threadIdx.x; j < S_CHUNK; j += THR_C) dst[j] = bins[j];
}

// ---------- Kernel D: reduce segment partials ----------
__global__ __launch_bounds__(256) void reduce_kernel(
    const float* __restrict__ partials, float* __restrict__ out, int B, int N)
{
    int n = blockIdx.x * blockDim.x + threadIdx.x;
    if (n >= N) return;
    int c = n >> 14;
    int j = n & (S_CHUNK - 1);
    const float* p = partials + ((size_t)c * B) * S_CHUNK + j;
    float sum = 0.0f;
    for (int s = 0; s < B; ++s) sum += p[(size_t)s * S_CHUNK];
    out[n] = sum;
}

// ---------- Fallback (tiny workspace): direct atomic scatter ----------
__global__ __launch_bounds__(256) void edge_sum_atomic_kernel(
    const int* __restrict__ centers, const int* __restrict__ neighbors,
    const float* __restrict__ eng, const int* __restrict__ atom_type,
    const float* __restrict__ scales, float* __restrict__ out, int E)
{
    __shared__ float s_scales[NUM_TYPES * NUM_TYPES];
    if (threadIdx.x < NUM_TYPES * NUM_TYPES) s_scales[threadIdx.x] = scales[threadIdx.x];
    __syncthreads();
    int tid = blockIdx.x * blockDim.x + threadIdx.x;
    int stride = gridDim.x * blockDim.x;
    for (int i = tid; i < E; i += stride) {
        int cn = centers[i];
        float v = eng[i] * s_scales[atom_type[cn] * NUM_TYPES + atom_type[neighbors[i]]] * FACTOR;
        unsafeAtomicAdd(&out[cn], v);
    }
}

extern "C" void kernel_launch(void* const* d_in, const int* in_sizes, int n_in,
                              void* d_out, int out_size, void* d_ws, size_t ws_size,
                              hipStream_t stream) {
    const int E = in_sizes[1];  // edge_eng element count
    const int N = in_sizes[2];  // atom_type element count
    const int* edge_index = (const int*)d_in[0];   // [2, E]
    const float* edge_eng = (const float*)d_in[1]; // [E, 1]
    const int* atom_type = (const int*)d_in[2];    // [N, 1]
    const float* scales = (const float*)d_in[3];   // [T, T]
    float* out = (float*)d_out;

    const int* centers = edge_index;
    const int* neighbors = edge_index + E;

    // ws layout: [pairs E*8B][tt N][blockhist NBLK*7][totals 7 | cursors 7][partials C*B*S]
    auto al = [](size_t x) { return (x + 255) & ~(size_t)255; };
    size_t pairs_sz = al((size_t)E * 8);
    size_t tt_sz    = al((size_t)N);
    size_t bh_sz    = al((size_t)NBLK_AB * C_MAX * 4);
    size_t tc_sz    = al(2 * C_MAX * 4);
    size_t fixed    = pairs_sz + tt_sz + bh_sz + tc_sz;
    size_t per_b    = (size_t)C_MAX * S_CHUNK * 4;   // 458.8 KB per segment

    int B = 0;
    if (N <= C_MAX * S_CHUNK && ws_size > fixed)
        B = (int)((ws_size - fixed) / per_b);
    if (B > B_MAX) B = B_MAX;

    if (B >= 2) {
        char* w = (char*)d_ws;
        uint2*         pairs     = (uint2*)w;
        unsigned char* tt        = (unsigned char*)(w + pairs_sz);
        unsigned int*  blockhist = (unsigned int*)(w + pairs_sz + tt_sz);
        unsigned int*  totals    = (unsigned int*)(w + pairs_sz + tt_sz + bh_sz);
        unsigned int*  cursors   = totals + C_MAX;
        float*         partials  = (float*)(w + fixed);

        hipMemsetAsync(totals, 0, 2 * C_MAX * sizeof(unsigned int), stream);
        count_kernel<<<NBLK_AB, THR_AB, 0, stream>>>(
            centers, atom_type, tt, blockhist, totals, E, N);
        scatter_kernel<<<NBLK_AB, THR_AB, 0, stream>>>(
            centers, neighbors, edge_eng, tt, scales, blockhist, totals, cursors, pairs, E);
        bucket_sum_kernel<<<C_MAX * B, THR_C, 0, stream>>>(pairs, totals, partials, B);
        reduce_kernel<<<(N + 255) / 256, 256, 0, stream>>>(partials, out, B, N);
    } else {
        hipMemsetAsync(d_out, 0, (size_t)out_size * sizeof(float), stream);
        edge_sum_atomic_kernel<<<2048, 256, 0, stream>>>(
            centers, neighbors, edge_eng, atom_type, scales, out, E);
    }
}

// Round 5
// 180.360 us; speedup vs baseline: 1.7254x; 1.7254x over previous
//
#include <hip/hip_runtime.h>

#define N_NODES 100000
#define NUM_TYPES 8
#define FACTOR 0.125f      // 1/sqrt(64)

#define S_CHUNK 25600      // nodes per chunk; 25600*4B = 100 KB LDS bins (1 block/CU)
#define C_CHUNKS 4         // 4*25600 = 102400 >= 100000
#define THR 1024
#define B_MAX 64           // segments per chunk -> grid = 4*64 = 256 blocks = 1/CU

// Fused single-pass-per-chunk kernel. Block (c,b): scans edge segment b (strided),
// and for edges whose center lies in chunk c, gathers the two atom types, applies
// the scale, and accumulates into 100KB LDS bins. Type gathers happen exactly once
// per edge across the whole grid (guarded), no intermediate val/pair arrays.
// Block mapping: c = blockIdx % 4 -> the 4 chunks of a segment are dispatched
// adjacently and sweep the SAME edge cache lines simultaneously -> each HBM line
// is reused by all 4 chunks while L2/L3-resident (cuts the 4x logical re-read).
__global__ __launch_bounds__(THR) void fused_chunk_sum_kernel(
    const int* __restrict__ centers,
    const int* __restrict__ neighbors,
    const float* __restrict__ eng,
    const int* __restrict__ atom_type,
    const float* __restrict__ scales,
    float* __restrict__ partials,          // [C_CHUNKS][B][S_CHUNK]
    int E, int B)
{
    __shared__ float bins[S_CHUNK];
    __shared__ float s_scales[NUM_TYPES * NUM_TYPES];

    const int c = blockIdx.x % C_CHUNKS;   // chunk (fast-varying -> co-scheduled)
    const int b = blockIdx.x / C_CHUNKS;   // edge segment

    if (threadIdx.x < NUM_TYPES * NUM_TYPES)
        s_scales[threadIdx.x] = scales[threadIdx.x] * FACTOR;   // fold FACTOR
    for (int j = threadIdx.x; j < S_CHUNK; j += THR) bins[j] = 0.0f;
    __syncthreads();

    const int base = c * S_CHUNK;
    const int n4 = E >> 2;

    for (int i = b * THR + (int)threadIdx.x; i < n4; i += B * THR) {
        int4   cc = ((const int4*)centers)[i];
        int4   nn = ((const int4*)neighbors)[i];
        float4 e  = ((const float4*)eng)[i];

        unsigned j0 = (unsigned)(cc.x - base);
        unsigned j1 = (unsigned)(cc.y - base);
        unsigned j2 = (unsigned)(cc.z - base);
        unsigned j3 = (unsigned)(cc.w - base);

        if (j0 < S_CHUNK)
            atomicAdd(&bins[j0], e.x * s_scales[atom_type[cc.x] * NUM_TYPES + atom_type[nn.x]]);
        if (j1 < S_CHUNK)
            atomicAdd(&bins[j1], e.y * s_scales[atom_type[cc.y] * NUM_TYPES + atom_type[nn.y]]);
        if (j2 < S_CHUNK)
            atomicAdd(&bins[j2], e.z * s_scales[atom_type[cc.z] * NUM_TYPES + atom_type[nn.z]]);
        if (j3 < S_CHUNK)
            atomicAdd(&bins[j3], e.w * s_scales[atom_type[cc.w] * NUM_TYPES + atom_type[nn.w]]);
    }

    // tail (E % 4) — dead for E = 6,400,000; handled by segment b==0 of each chunk
    if (b == 0) {
        for (int i = (n4 << 2) + (int)threadIdx.x; i < E; i += THR) {
            int cn = centers[i];
            unsigned j = (unsigned)(cn - base);
            if (j < S_CHUNK)
                atomicAdd(&bins[j], eng[i] * s_scales[atom_type[cn] * NUM_TYPES + atom_type[neighbors[i]]]);
        }
    }

    __syncthreads();
    float* dst = partials + ((size_t)c * B + b) * S_CHUNK;
    for (int j = threadIdx.x; j < S_CHUNK; j += THR) dst[j] = bins[j];
}

// out[n] = sum over B segment-partials of node n's chunk. Coalesced within a chunk row.
__global__ __launch_bounds__(256) void reduce_kernel(
    const float* __restrict__ partials, float* __restrict__ out, int B, int N)
{
    int n = blockIdx.x * blockDim.x + threadIdx.x;
    if (n >= N) return;
    int c = n / S_CHUNK;
    int j = n - c * S_CHUNK;
    const float* p = partials + ((size_t)c * B) * S_CHUNK + j;
    float s = 0.0f;
    for (int b = 0; b < B; ++b) s += p[(size_t)b * S_CHUNK];
    out[n] = s;
}

// Fallback (tiny workspace only): direct atomic scatter into out.
__global__ __launch_bounds__(256) void edge_sum_atomic_kernel(
    const int* __restrict__ centers, const int* __restrict__ neighbors,
    const float* __restrict__ eng, const int* __restrict__ atom_type,
    const float* __restrict__ scales, float* __restrict__ out, int E)
{
    __shared__ float s_scales[NUM_TYPES * NUM_TYPES];
    if (threadIdx.x < NUM_TYPES * NUM_TYPES) s_scales[threadIdx.x] = scales[threadIdx.x];
    __syncthreads();
    int tid = blockIdx.x * blockDim.x + threadIdx.x;
    int stride = gridDim.x * blockDim.x;
    for (int i = tid; i < E; i += stride) {
        int cn = centers[i];
        float v = eng[i] * s_scales[atom_type[cn] * NUM_TYPES + atom_type[neighbors[i]]] * FACTOR;
        unsafeAtomicAdd(&out[cn], v);
    }
}

extern "C" void kernel_launch(void* const* d_in, const int* in_sizes, int n_in,
                              void* d_out, int out_size, void* d_ws, size_t ws_size,
                              hipStream_t stream) {
    const int E = in_sizes[1];  // edge_eng element count
    const int N = in_sizes[2];  // atom_type element count
    const int* edge_index = (const int*)d_in[0];   // [2, E]
    const float* edge_eng = (const float*)d_in[1]; // [E, 1]
    const int* atom_type = (const int*)d_in[2];    // [N, 1]
    const float* scales = (const float*)d_in[3];   // [T, T]
    float* out = (float*)d_out;

    const int* centers = edge_index;
    const int* neighbors = edge_index + E;

    // Workspace: C * B * S_CHUNK floats (B=64 -> 26.2 MB). Shrink B if ws small.
    size_t per_b = (size_t)C_CHUNKS * S_CHUNK * sizeof(float);  // 409.6 KB per segment
    int B = (int)(ws_size / per_b);
    if (B > B_MAX) B = B_MAX;

    if (N <= C_CHUNKS * S_CHUNK && B >= 8) {
        float* partials = (float*)d_ws;
        // No memset needed: every block writes its full bin array.
        fused_chunk_sum_kernel<<<C_CHUNKS * B, THR, 0, stream>>>(
            centers, neighbors, edge_eng, atom_type, scales, partials, E, B);
        reduce_kernel<<<(N + 255) / 256, 256, 0, stream>>>(partials, out, B, N);
    } else {
        hipMemsetAsync(d_out, 0, (size_t)out_size * sizeof(float), stream);
        edge_sum_atomic_kernel<<<2048, 256, 0, stream>>>(
            centers, neighbors, edge_eng, atom_type, scales, out, E);
    }
}